// Round 2
// baseline (1632.256 us; speedup 1.0000x reference)
//
#include <hip/hip_runtime.h>
#include <hip/hip_bf16.h>

#define NN 131072   // nodes per side
#define NE 524288   // edges per side
#define NB 1024     // batch (graphs per side)

__device__ __forceinline__ float wsum(float v){
#pragma unroll
  for (int o = 32; o > 0; o >>= 1) v += __shfl_xor(v, o, 64);
  return v;
}

// ---------------- CSR build ----------------
__global__ void k_zero(int* __restrict__ p, int n){
  int i = blockIdx.x * 256 + threadIdx.x;
  if (i < n) p[i] = 0;
}

__global__ void k_hist(const int* __restrict__ ei, int* __restrict__ cnt){
  int e = blockIdx.x * 256 + threadIdx.x;
  if (e < NE) atomicAdd(&cnt[ei[NE + e]], 1);
}

__global__ void k_scan1(const int* __restrict__ cnt, int* __restrict__ rowptr,
                        int* __restrict__ bsum){
  __shared__ int sh[256];
  int i = blockIdx.x * 256 + threadIdx.x;
  int v = cnt[i];
  sh[threadIdx.x] = v; __syncthreads();
  for (int off = 1; off < 256; off <<= 1){
    int t = (threadIdx.x >= off) ? sh[threadIdx.x - off] : 0;
    __syncthreads();
    sh[threadIdx.x] += t;
    __syncthreads();
  }
  int incl = sh[threadIdx.x];
  rowptr[i] = incl - v;
  if (threadIdx.x == 255) bsum[blockIdx.x] = incl;
}

__global__ void k_scan2(int* __restrict__ bsum){
  __shared__ int sh[512];
  int v = bsum[threadIdx.x];
  sh[threadIdx.x] = v; __syncthreads();
  for (int off = 1; off < 512; off <<= 1){
    int t = (threadIdx.x >= off) ? sh[threadIdx.x - off] : 0;
    __syncthreads();
    sh[threadIdx.x] += t;
    __syncthreads();
  }
  bsum[threadIdx.x] = sh[threadIdx.x] - v;  // exclusive
}

__global__ void k_scan3(int* __restrict__ rowptr, const int* __restrict__ bsum,
                        int* __restrict__ cursor){
  int i = blockIdx.x * 256 + threadIdx.x;
  int v = rowptr[i] + bsum[blockIdx.x];
  rowptr[i] = v;
  cursor[i] = v;
  if (i == 0) rowptr[NN] = NE;
}

__global__ void k_scatter(const int* __restrict__ ei, const int* __restrict__ et,
                          int* __restrict__ cursor, int* __restrict__ csrc,
                          int* __restrict__ cet){
  int e = blockIdx.x * 256 + threadIdx.x;
  if (e < NE){
    int d = ei[NE + e];
    int p = atomicAdd(&cursor[d], 1);
    csrc[p] = ei[e];
    cet[p]  = et[e];
  }
}

// ---------------- feature gather ----------------
__global__ void k_gather(const int* __restrict__ nodes, const float* __restrict__ wemb,
                         float* __restrict__ x){
  int t = blockIdx.x * 256 + threadIdx.x;       // t < NN*64
  int n = t >> 6, l = t & 63;
  x[t] = wemb[(long)nodes[n] * 64 + l];
}

// ---------------- rtab[l*4+t] = rel[l][t] . att[l][2] ----------------
__global__ void k_rtab(const float* __restrict__ rel, const float* __restrict__ att,
                       float* __restrict__ rtab){
  int lane = threadIdx.x & 63, w = threadIdx.x >> 6;  // 8 waves: (layer, reltype)
  int l = w >> 2, t = w & 3;
  float p = rel[l * 256 + t * 64 + lane] * att[l * 192 + 128 + lane];
  p = wsum(p);
  if (lane == 0) rtab[w] = p;
}

// ---------------- per-interaction prep: rep (inter) + queries (trans layers) ----------------
__global__ void k_prep(const int* __restrict__ ids, const float* __restrict__ emb,
                       const float* __restrict__ interW, const float* __restrict__ interB,
                       const float* __restrict__ transW, const float* __restrict__ transB,
                       float* __restrict__ xfm, int repOff, float* __restrict__ q){
  int lane = threadIdx.x & 63, w = threadIdx.x >> 6;
  int b = blockIdx.x * 4 + w;
  float xe = emb[(long)ids[b] * 64 + lane];
  float o = interB[lane];
#pragma unroll
  for (int k = 0; k < 64; k++) o += __shfl(xe, k, 64) * interW[k * 64 + lane];
  xfm[b * 384 + repOff + lane] = fmaxf(o, 0.f);
  for (int l = 0; l < 2; l++){
    float t = transB[l * 64 + lane];
#pragma unroll
    for (int k = 0; k < 64; k++) t += __shfl(xe, k, 64) * transW[l * 4096 + k * 64 + lane];
    q[l * NB * 64 + b * 64 + lane] = fmaxf(t, 0.f);
  }
}

// ---------------- h = x @ W + b  (+ fused a0/a1 attention dots) ----------------
__global__ void k_gemm_h(const float* __restrict__ x, const float* __restrict__ W,
                         const float* __restrict__ bias, const float* __restrict__ att,
                         float* __restrict__ h, float* __restrict__ a0, float* __restrict__ a1){
  __shared__ float Ws[4096];
  __shared__ float bs[64], at0[64], at1[64];
  int tid = threadIdx.x;
  for (int i = tid; i < 4096; i += 256) Ws[i] = W[i];
  if (tid < 64){ bs[tid] = bias[tid]; at0[tid] = att[tid]; at1[tid] = att[64 + tid]; }
  __syncthreads();
  int lane = tid & 63, w = tid >> 6;
  long n0 = (long)blockIdx.x * 16 + w * 4;
  float xv0 = x[(n0 + 0) * 64 + lane];
  float xv1 = x[(n0 + 1) * 64 + lane];
  float xv2 = x[(n0 + 2) * 64 + lane];
  float xv3 = x[(n0 + 3) * 64 + lane];
  float h0 = bs[lane], h1 = bs[lane], h2 = bs[lane], h3 = bs[lane];
#pragma unroll
  for (int k = 0; k < 64; k++){
    float wv = Ws[k * 64 + lane];
    h0 += __shfl(xv0, k, 64) * wv;
    h1 += __shfl(xv1, k, 64) * wv;
    h2 += __shfl(xv2, k, 64) * wv;
    h3 += __shfl(xv3, k, 64) * wv;
  }
  h[(n0 + 0) * 64 + lane] = h0;
  h[(n0 + 1) * 64 + lane] = h1;
  h[(n0 + 2) * 64 + lane] = h2;
  h[(n0 + 3) * 64 + lane] = h3;
  float s;
  s = wsum(h0 * at0[lane]); if (lane == 0) a0[n0 + 0] = s;
  s = wsum(h0 * at1[lane]); if (lane == 0) a1[n0 + 0] = s;
  s = wsum(h1 * at0[lane]); if (lane == 0) a0[n0 + 1] = s;
  s = wsum(h1 * at1[lane]); if (lane == 0) a1[n0 + 1] = s;
  s = wsum(h2 * at0[lane]); if (lane == 0) a0[n0 + 2] = s;
  s = wsum(h2 * at1[lane]); if (lane == 0) a1[n0 + 2] = s;
  s = wsum(h3 * at0[lane]); if (lane == 0) a0[n0 + 3] = s;
  s = wsum(h3 * at1[lane]); if (lane == 0) a1[n0 + 3] = s;
}

// ---------------- GAT aggregation: wave per dst node ----------------
__global__ void k_agg(const int* __restrict__ rowptr, const int* __restrict__ csrc,
                      const int* __restrict__ cet, const float* __restrict__ a0,
                      const float* __restrict__ a1, const float* __restrict__ rtab, int l4,
                      const float* __restrict__ h, float* __restrict__ xo){
  int lane = threadIdx.x & 63, w = threadIdx.x >> 6;
  int n = blockIdx.x * 4 + w;
  int s0 = rowptr[n], s1 = rowptr[n + 1];
  float a1n = a1[n];
  float den = 0.f;
  for (int base = s0; base < s1; base += 64){
    int idx = base + lane;
    float ex = 0.f;
    if (idx < s1){
      float e = a0[csrc[idx]] + a1n + rtab[l4 + cet[idx]];
      e = (e > 0.f) ? e : 0.2f * e;
      ex = __expf(e);
    }
    den += wsum(ex);
  }
  float inv = 1.f / (den + 1e-16f);
  float acc = 0.f;
  for (int base = s0; base < s1; base += 64){
    int idx = base + lane;
    float ex = 0.f; int src = 0;
    if (idx < s1){
      src = csrc[idx];
      float e = a0[src] + a1n + rtab[l4 + cet[idx]];
      e = (e > 0.f) ? e : 0.2f * e;
      ex = __expf(e);
    }
    int cnt = min(64, s1 - base);
    for (int j = 0; j < cnt; j++){
      float aj = __shfl(ex, j, 64) * inv;
      int sj = __shfl(src, j, 64);
      acc += aj * h[(long)sj * 64 + lane];
    }
  }
  xo[(long)n * 64 + lane] = fmaxf(acc, 0.f);
}

// ---------------- y = x @ pool_W, score = sigmoid(<y,q>/8), xs = x*score ----------------
__global__ void k_score(const float* __restrict__ x, const float* __restrict__ poolW,
                        const float* __restrict__ q, const int* __restrict__ batch,
                        float* __restrict__ xs){
  __shared__ float Ws[4096];
  int tid = threadIdx.x;
  for (int i = tid; i < 4096; i += 256) Ws[i] = poolW[i];
  __syncthreads();
  int lane = tid & 63, w = tid >> 6;
  long n0 = (long)blockIdx.x * 16 + w * 4;
  float xv0 = x[(n0 + 0) * 64 + lane];
  float xv1 = x[(n0 + 1) * 64 + lane];
  float xv2 = x[(n0 + 2) * 64 + lane];
  float xv3 = x[(n0 + 3) * 64 + lane];
  float y0 = 0.f, y1 = 0.f, y2 = 0.f, y3 = 0.f;
#pragma unroll
  for (int k = 0; k < 64; k++){
    float wv = Ws[k * 64 + lane];
    y0 += __shfl(xv0, k, 64) * wv;
    y1 += __shfl(xv1, k, 64) * wv;
    y2 += __shfl(xv2, k, 64) * wv;
    y3 += __shfl(xv3, k, 64) * wv;
  }
  {
    float s = wsum(y0 * q[(long)batch[n0 + 0] * 64 + lane]);
    float sc = 1.f / (1.f + __expf(-s * 0.125f));
    xs[(n0 + 0) * 64 + lane] = xv0 * sc;
  }
  {
    float s = wsum(y1 * q[(long)batch[n0 + 1] * 64 + lane]);
    float sc = 1.f / (1.f + __expf(-s * 0.125f));
    xs[(n0 + 1) * 64 + lane] = xv1 * sc;
  }
  {
    float s = wsum(y2 * q[(long)batch[n0 + 2] * 64 + lane]);
    float sc = 1.f / (1.f + __expf(-s * 0.125f));
    xs[(n0 + 2) * 64 + lane] = xv2 * sc;
  }
  {
    float s = wsum(y3 * q[(long)batch[n0 + 3] * 64 + lane]);
    float sc = 1.f / (1.f + __expf(-s * 0.125f));
    xs[(n0 + 3) * 64 + lane] = xv3 * sc;
  }
}

// ---------------- segment max pool (contiguous 128-node graphs) + trans_w ----------------
__global__ void k_pool(const float* __restrict__ xs, const float* __restrict__ twW,
                       const float* __restrict__ twb, float* __restrict__ xfm, int off){
  int lane = threadIdx.x & 63, w = threadIdx.x >> 6;
  int b = blockIdx.x * 4 + w;
  float m = 0.f;   // values are >= 0 (relu * sigmoid-scale)
  for (int k = 0; k < 128; k++)
    m = fmaxf(m, xs[((long)b * 128 + k) * 64 + lane]);
  float o = twb[lane];
#pragma unroll
  for (int d = 0; d < 64; d++) o += __shfl(m, d, 64) * twW[d * 64 + lane];
  xfm[b * 384 + off + lane] = fmaxf(o, 0.f);
}

// ---------------- FM head ----------------
__global__ void k_fm(const float* __restrict__ xfm, const float* __restrict__ V,
                     const float* __restrict__ fw, const float* __restrict__ bu,
                     const float* __restrict__ bi, const float* __restrict__ b0,
                     const int* __restrict__ uid, const int* __restrict__ iid,
                     float* __restrict__ out){
  __shared__ float xsh[384];
  __shared__ float red[6];
  int b = blockIdx.x, j = threadIdx.x;
  xsh[j] = xfm[b * 384 + j];
  __syncthreads();
  float xv = 0.f, vv = 0.f;
  for (int k = 0; k < 384; k++){
    float xk = xsh[k];
    float v = V[k * 384 + j];
    xv += xk * v;
    vv += xk * xk * v * v;
  }
  float part = 0.5f * (xv * xv - vv) + xsh[j] * fw[j];
  part = wsum(part);
  int lane = j & 63, w = j >> 6;
  if (lane == 0) red[w] = part;
  __syncthreads();
  if (j == 0){
    float t = red[0] + red[1] + red[2] + red[3] + red[4] + red[5];
    t += bu[uid[b]] + bi[iid[b]] + b0[0];
    out[b] = t;
  }
}

extern "C" void kernel_launch(void* const* d_in, const int* in_sizes, int n_in,
                              void* d_out, int out_size, void* d_ws, size_t ws_size,
                              hipStream_t stream) {
  const int* uid      = (const int*)d_in[0];
  const int* iid      = (const int*)d_in[1];
  const int* u_nodes  = (const int*)d_in[2];
  const int* i_nodes  = (const int*)d_in[3];
  const int* u_ei     = (const int*)d_in[4];
  const int* i_ei     = (const int*)d_in[5];
  const int* u_et     = (const int*)d_in[6];
  const int* i_et     = (const int*)d_in[7];
  const int* u_batch  = (const int*)d_in[8];
  const int* i_batch  = (const int*)d_in[9];
  const float* user_emb = (const float*)d_in[10];
  const float* item_emb = (const float*)d_in[11];
  const float* word_emb = (const float*)d_in[12];
  const float* trans_u_W = (const float*)d_in[13];
  const float* trans_u_b = (const float*)d_in[14];
  const float* trans_i_W = (const float*)d_in[15];
  const float* trans_i_b = (const float*)d_in[16];
  const float* trans_w_W = (const float*)d_in[17];
  const float* trans_w_b = (const float*)d_in[18];
  const float* inter_u_W = (const float*)d_in[19];
  const float* inter_u_b = (const float*)d_in[20];
  const float* inter_i_W = (const float*)d_in[21];
  const float* inter_i_b = (const float*)d_in[22];
  const float* conv_u_W  = (const float*)d_in[23];
  const float* conv_u_b  = (const float*)d_in[24];
  const float* conv_u_att= (const float*)d_in[25];
  const float* conv_u_rel= (const float*)d_in[26];
  const float* conv_i_W  = (const float*)d_in[27];
  const float* conv_i_b  = (const float*)d_in[28];
  const float* conv_i_att= (const float*)d_in[29];
  const float* conv_i_rel= (const float*)d_in[30];
  const float* pool_W    = (const float*)d_in[31];
  const float* fm_w      = (const float*)d_in[32];
  const float* fm_V      = (const float*)d_in[33];
  const float* fm_bias_u = (const float*)d_in[34];
  const float* fm_bias_i = (const float*)d_in[35];
  const float* fm_bias   = (const float*)d_in[36];
  float* out = (float*)d_out;

  // workspace carve-up (ping-pong node buffers; x dead after gemm_h)
  char* w = (char*)d_ws;
  float* buf0 = (float*)w;          w += (size_t)NN * 64 * 4;   // 32 MB
  float* buf1 = (float*)w;          w += (size_t)NN * 64 * 4;   // 32 MB
  float* a0   = (float*)w;          w += (size_t)NN * 4;
  float* a1   = (float*)w;          w += (size_t)NN * 4;
  int* rowptr = (int*)w;            w += (size_t)(NN + 256) * 4;
  int* cursor = (int*)w;            w += (size_t)NN * 4;
  int* cnt    = (int*)w;            w += (size_t)NN * 4;
  int* csrc   = (int*)w;            w += (size_t)NE * 4;
  int* cet    = (int*)w;            w += (size_t)NE * 4;
  int* bsum   = (int*)w;            w += 4096;
  float* rtab = (float*)w;          w += 256;
  float* qbuf = (float*)w;          w += (size_t)2 * NB * 64 * 4;
  float* xfm  = (float*)w;          w += (size_t)NB * 384 * 4;

  for (int side = 0; side < 2; ++side){
    const int*  nodes = side ? i_nodes : u_nodes;
    const int*  ei    = side ? i_ei    : u_ei;
    const int*  et    = side ? i_et    : u_et;
    const int*  batch = side ? i_batch : u_batch;
    const float* convW = side ? conv_i_W   : conv_u_W;
    const float* convB = side ? conv_i_b   : conv_u_b;
    const float* att   = side ? conv_i_att : conv_u_att;
    const float* rel   = side ? conv_i_rel : conv_u_rel;
    const int*  ids   = side ? iid : uid;
    const float* emb  = side ? item_emb : user_emb;
    const float* intW = side ? inter_i_W : inter_u_W;
    const float* intB = side ? inter_i_b : inter_u_b;
    const float* trW  = side ? trans_i_W : trans_u_W;
    const float* trB  = side ? trans_i_b : trans_u_b;
    int repOff  = side ? 192 : 0;
    int poolOff = side ? 256 : 64;

    k_zero   <<<NN / 256, 256, 0, stream>>>(cnt, NN);
    k_hist   <<<NE / 256, 256, 0, stream>>>(ei, cnt);
    k_scan1  <<<NN / 256, 256, 0, stream>>>(cnt, rowptr, bsum);
    k_scan2  <<<1, 512, 0, stream>>>(bsum);
    k_scan3  <<<NN / 256, 256, 0, stream>>>(rowptr, bsum, cursor);
    k_scatter<<<NE / 256, 256, 0, stream>>>(ei, et, cursor, csrc, cet);
    k_gather <<<NN * 64 / 256, 256, 0, stream>>>(nodes, word_emb, buf0);
    k_rtab   <<<1, 512, 0, stream>>>(rel, att, rtab);
    k_prep   <<<NB / 4, 256, 0, stream>>>(ids, emb, intW, intB, trW, trB, xfm, repOff, qbuf);

    // layer l: x in A -> h in B -> x2 in A -> xs in B  (A/B alternate per layer)
    float* A = buf0; float* Bv = buf1;
    for (int l = 0; l < 2; ++l){
      k_gemm_h<<<NN / 16, 256, 0, stream>>>(A, convW + l * 4096, convB + l * 64,
                                            att + l * 192, Bv, a0, a1);
      k_agg   <<<NN / 4, 256, 0, stream>>>(rowptr, csrc, cet, a0, a1, rtab, l * 4,
                                           Bv, A);
      k_score <<<NN / 16, 256, 0, stream>>>(A, pool_W, qbuf + (size_t)l * NB * 64,
                                            batch, Bv);
      k_pool  <<<NB / 4, 256, 0, stream>>>(Bv, trans_w_W + l * 4096, trans_w_b + l * 64,
                                           xfm, poolOff + l * 64);
      float* t = A; A = Bv; Bv = t;
    }
  }

  k_fm<<<NB, 384, 0, stream>>>(xfm, fm_V, fm_w, fm_bias_u, fm_bias_i, fm_bias,
                               uid, iid, out);
}

// Round 3
// 751.702 us; speedup vs baseline: 2.1714x; 2.1714x over previous
//
#include <hip/hip_runtime.h>
#include <hip/hip_bf16.h>

#define NN 131072   // nodes per side
#define NE 524288   // edges per side
#define NB 1024     // batch (graphs per side)

typedef __attribute__((ext_vector_type(8))) short short8;   // 8 bf16
typedef __attribute__((ext_vector_type(4))) float f32x4;

__device__ __forceinline__ float wsum(float v){
#pragma unroll
  for (int o = 32; o > 0; o >>= 1) v += __shfl_xor(v, o, 64);
  return v;
}
__device__ __forceinline__ short f2bs(float f){
  __hip_bfloat16 t = __float2bfloat16(f);
  union { __hip_bfloat16 b; short s; } u; u.b = t; return u.s;
}
__device__ __forceinline__ float bs2f(short s){
  return __uint_as_float(((unsigned)(unsigned short)s) << 16);
}

// ---------------- CSR build ----------------
__global__ void k_zero(int* __restrict__ p, int n){
  int i = blockIdx.x * 256 + threadIdx.x;
  if (i < n) p[i] = 0;
}

__global__ void k_hist(const int* __restrict__ ei, int* __restrict__ cnt){
  int e = blockIdx.x * 256 + threadIdx.x;
  if (e < NE) atomicAdd(&cnt[ei[NE + e]], 1);
}

__global__ void k_scan1(const int* __restrict__ cnt, int* __restrict__ rowptr,
                        int* __restrict__ bsum){
  __shared__ int sh[256];
  int i = blockIdx.x * 256 + threadIdx.x;
  int v = cnt[i];
  sh[threadIdx.x] = v; __syncthreads();
  for (int off = 1; off < 256; off <<= 1){
    int t = (threadIdx.x >= off) ? sh[threadIdx.x - off] : 0;
    __syncthreads();
    sh[threadIdx.x] += t;
    __syncthreads();
  }
  int incl = sh[threadIdx.x];
  rowptr[i] = incl - v;
  if (threadIdx.x == 255) bsum[blockIdx.x] = incl;
}

__global__ void k_scan2(int* __restrict__ bsum){
  __shared__ int sh[512];
  int v = bsum[threadIdx.x];
  sh[threadIdx.x] = v; __syncthreads();
  for (int off = 1; off < 512; off <<= 1){
    int t = (threadIdx.x >= off) ? sh[threadIdx.x - off] : 0;
    __syncthreads();
    sh[threadIdx.x] += t;
    __syncthreads();
  }
  bsum[threadIdx.x] = sh[threadIdx.x] - v;  // exclusive
}

__global__ void k_scan3(int* __restrict__ rowptr, const int* __restrict__ bsum,
                        int* __restrict__ cursor){
  int i = blockIdx.x * 256 + threadIdx.x;
  int v = rowptr[i] + bsum[blockIdx.x];
  rowptr[i] = v;
  cursor[i] = v;
  if (i == 0) rowptr[NN] = NE;
}

__global__ void k_scatter(const int* __restrict__ ei, const int* __restrict__ et,
                          int* __restrict__ cursor, int* __restrict__ csrc,
                          int* __restrict__ cet){
  int e = blockIdx.x * 256 + threadIdx.x;
  if (e < NE){
    int d = ei[NE + e];
    int p = atomicAdd(&cursor[d], 1);
    csrc[p] = ei[e];
    cet[p]  = et[e];
  }
}

// ---------------- feature gather (fp32 emb -> bf16 node features) ----------------
__global__ void k_gather(const int* __restrict__ nodes, const float* __restrict__ wemb,
                         short* __restrict__ x){
  int t = blockIdx.x * 256 + threadIdx.x;       // t < NN*64
  int n = t >> 6, c = t & 63;
  x[t] = f2bs(wemb[(long)nodes[n] * 64 + c]);
}

// ---------------- weight frag packing: 64x64 fp32 -> MFMA B-frags bf16 ----------------
// frag[((mat*4+t)*2+h)*64 + lane][j] = bf16( W[mat][k=h*32+(lane>>4)*8+j][n=t*16+(lane&15)] )
__global__ void k_wfrag(const float* __restrict__ W, short8* __restrict__ frag, int nmat){
  int g = blockIdx.x * 256 + threadIdx.x;
  int lane = g & 63, rest = g >> 6;
  int hh = rest & 1, t = (rest >> 1) & 3, mat = rest >> 3;
  if (mat >= nmat) return;
  int m = lane & 15, q = lane >> 4;
  short8 v;
#pragma unroll
  for (int j = 0; j < 8; j++){
    int k = hh * 32 + q * 8 + j;
    int n = t * 16 + m;
    v[j] = f2bs(W[mat * 4096 + k * 64 + n]);
  }
  frag[g] = v;
}

// ---------------- per-side misc: waA[l][a] = W_l @ att_a ; ba[l][a] = b_l . att_a ; rtab ----------------
__global__ void k_wmisc(const float* __restrict__ W, const float* __restrict__ bias,
                        const float* __restrict__ att, const float* __restrict__ rel,
                        float* __restrict__ waA, float* __restrict__ ba,
                        float* __restrict__ rtab){
  int tid = threadIdx.x;
  int l = tid >> 7, a = (tid >> 6) & 1, kk = tid & 63;
  float s = 0.f;
  for (int c = 0; c < 64; c++) s += W[l * 4096 + kk * 64 + c] * att[l * 192 + a * 64 + c];
  waA[(l * 2 + a) * 64 + kk] = s;
  if (tid < 4){
    int l2 = tid >> 1, a2 = tid & 1;
    float sb = 0.f;
    for (int c = 0; c < 64; c++) sb += bias[l2 * 64 + c] * att[l2 * 192 + a2 * 64 + c];
    ba[tid] = sb;
  }
  if (tid >= 4 && tid < 12){
    int id = tid - 4, l2 = id >> 2, tt = id & 3;
    float sr = 0.f;
    for (int c = 0; c < 64; c++) sr += rel[l2 * 256 + tt * 64 + c] * att[l2 * 192 + 128 + c];
    rtab[id] = sr;
  }
}

// ---------------- per-interaction prep: rep (inter) + queries (trans layers) ----------------
__global__ void k_prep(const int* __restrict__ ids, const float* __restrict__ emb,
                       const float* __restrict__ interW, const float* __restrict__ interB,
                       const float* __restrict__ transW, const float* __restrict__ transB,
                       float* __restrict__ xfm, int repOff, float* __restrict__ q){
  int lane = threadIdx.x & 63, w = threadIdx.x >> 6;
  int b = blockIdx.x * 4 + w;
  float xe = emb[(long)ids[b] * 64 + lane];
  float o = interB[lane];
#pragma unroll
  for (int k = 0; k < 64; k++) o += __shfl(xe, k, 64) * interW[k * 64 + lane];
  xfm[b * 384 + repOff + lane] = fmaxf(o, 0.f);
  for (int l = 0; l < 2; l++){
    float t = transB[l * 64 + lane];
#pragma unroll
    for (int k = 0; k < 64; k++) t += __shfl(xe, k, 64) * transW[l * 4096 + k * 64 + lane];
    q[l * NB * 64 + b * 64 + lane] = fmaxf(t, 0.f);
  }
}

// ---------------- MFMA: h = x @ W + b (fp32 out) ; fused a0/a1 = x.waA + ba ----------------
__global__ __launch_bounds__(256) void k_gemm_h(
    const short* __restrict__ x, const short8* __restrict__ wfrag,
    const float* __restrict__ bias, const float* __restrict__ waA,
    const float* __restrict__ ba, float* __restrict__ h,
    float* __restrict__ a0, float* __restrict__ a1){
  int lane = threadIdx.x & 63, w = threadIdx.x >> 6;
  int m = lane & 15, q = lane >> 4;
  short8 Bf[4][2];
#pragma unroll
  for (int t = 0; t < 4; t++)
#pragma unroll
    for (int hh = 0; hh < 2; hh++)
      Bf[t][hh] = wfrag[(t * 2 + hh) * 64 + lane];
  float bs[4];
#pragma unroll
  for (int t = 0; t < 4; t++) bs[t] = bias[t * 16 + m];
  float w0[16], w1[16];
#pragma unroll
  for (int j = 0; j < 8; j++){
    w0[j]     = waA[q * 8 + j];
    w0[8 + j] = waA[32 + q * 8 + j];
    w1[j]     = waA[64 + q * 8 + j];
    w1[8 + j] = waA[96 + q * 8 + j];
  }
  float ba0 = ba[0], ba1 = ba[1];
  long n0 = (long)blockIdx.x * 128 + w * 32;
  for (int rb = 0; rb < 2; rb++, n0 += 16){
    const short8* xr = (const short8*)(x + (n0 + m) * 64);
    short8 A0 = xr[q];
    short8 A1 = xr[q + 4];
    f32x4 acc[4];
#pragma unroll
    for (int t = 0; t < 4; t++){
      acc[t] = (f32x4){bs[t], bs[t], bs[t], bs[t]};
      acc[t] = __builtin_amdgcn_mfma_f32_16x16x32_bf16(A0, Bf[t][0], acc[t], 0, 0, 0);
      acc[t] = __builtin_amdgcn_mfma_f32_16x16x32_bf16(A1, Bf[t][1], acc[t], 0, 0, 0);
    }
#pragma unroll
    for (int t = 0; t < 4; t++)
#pragma unroll
      for (int r = 0; r < 4; r++)
        h[(n0 + q * 4 + r) * 64 + t * 16 + m] = acc[t][r];
    float p0 = 0.f, p1 = 0.f;
#pragma unroll
    for (int j = 0; j < 8; j++){
      float va = bs2f(A0[j]);
      float vb = bs2f(A1[j]);
      p0 += va * w0[j] + vb * w0[8 + j];
      p1 += va * w1[j] + vb * w1[8 + j];
    }
    p0 += __shfl_xor(p0, 16, 64); p0 += __shfl_xor(p0, 32, 64);
    p1 += __shfl_xor(p1, 16, 64); p1 += __shfl_xor(p1, 32, 64);
    if (q == 0){ a0[n0 + m] = p0 + ba0; a1[n0 + m] = p1 + ba1; }
  }
}

// ---------------- GAT aggregation: wave per dst node (h fp32 in, bf16 out) ----------------
__global__ void k_agg(const int* __restrict__ rowptr, const int* __restrict__ csrc,
                      const int* __restrict__ cet, const float* __restrict__ a0,
                      const float* __restrict__ a1, const float* __restrict__ rtab, int l4,
                      const float* __restrict__ h, short* __restrict__ xo){
  int lane = threadIdx.x & 63, w = threadIdx.x >> 6;
  int n = blockIdx.x * 4 + w;
  int s0 = rowptr[n], s1 = rowptr[n + 1];
  float a1n = a1[n];
  float den = 0.f;
  for (int base = s0; base < s1; base += 64){
    int idx = base + lane;
    float ex = 0.f;
    if (idx < s1){
      float e = a0[csrc[idx]] + a1n + rtab[l4 + cet[idx]];
      e = (e > 0.f) ? e : 0.2f * e;
      ex = __expf(e);
    }
    den += wsum(ex);
  }
  float inv = 1.f / (den + 1e-16f);
  float acc = 0.f;
  for (int base = s0; base < s1; base += 64){
    int idx = base + lane;
    float ex = 0.f; int src = 0;
    if (idx < s1){
      src = csrc[idx];
      float e = a0[src] + a1n + rtab[l4 + cet[idx]];
      e = (e > 0.f) ? e : 0.2f * e;
      ex = __expf(e);
    }
    int cnt = min(64, s1 - base);
    for (int j = 0; j < cnt; j++){
      float aj = __shfl(ex, j, 64) * inv;
      int sj = __shfl(src, j, 64);
      acc += aj * h[(long)sj * 64 + lane];
    }
  }
  xo[(long)n * 64 + lane] = f2bs(fmaxf(acc, 0.f));
}

// ---------------- fused: y=x@poolW (MFMA), gate=sigmoid(<y,q>/8), gmp(x*gate), trans_w ----------------
__global__ __launch_bounds__(256) void k_scorepool(
    const short* __restrict__ x, const short8* __restrict__ pfrag,
    const float* __restrict__ q, const float* __restrict__ twW,
    const float* __restrict__ twb, float* __restrict__ xfm, int off){
  __shared__ float gates[128];
  __shared__ float red[4][64];
  int b = blockIdx.x;
  int tid = threadIdx.x, lane = tid & 63, w = tid >> 6;
  int m = lane & 15, qd = lane >> 4;
  short8 Bf[4][2];
#pragma unroll
  for (int t = 0; t < 4; t++)
#pragma unroll
    for (int hh = 0; hh < 2; hh++)
      Bf[t][hh] = pfrag[(t * 2 + hh) * 64 + lane];
  float qv[4];
#pragma unroll
  for (int t = 0; t < 4; t++) qv[t] = q[b * 64 + t * 16 + m];
  long base = (long)b * 128;
  for (int rb = 0; rb < 2; rb++){
    long n0 = base + w * 32 + rb * 16;
    const short8* xr = (const short8*)(x + (n0 + m) * 64);
    short8 A0 = xr[qd];
    short8 A1 = xr[qd + 4];
    f32x4 acc[4];
#pragma unroll
    for (int t = 0; t < 4; t++){
      acc[t] = (f32x4){0.f, 0.f, 0.f, 0.f};
      acc[t] = __builtin_amdgcn_mfma_f32_16x16x32_bf16(A0, Bf[t][0], acc[t], 0, 0, 0);
      acc[t] = __builtin_amdgcn_mfma_f32_16x16x32_bf16(A1, Bf[t][1], acc[t], 0, 0, 0);
    }
#pragma unroll
    for (int r = 0; r < 4; r++){
      float p = acc[0][r] * qv[0] + acc[1][r] * qv[1] + acc[2][r] * qv[2] + acc[3][r] * qv[3];
      p += __shfl_xor(p, 1, 64); p += __shfl_xor(p, 2, 64);
      p += __shfl_xor(p, 4, 64); p += __shfl_xor(p, 8, 64);
      if (m == 0)
        gates[w * 32 + rb * 16 + qd * 4 + r] = 1.f / (1.f + __expf(-p * 0.125f));
    }
  }
  __syncthreads();
  float mx = 0.f;
  for (int n = w * 32; n < w * 32 + 32; n++){
    float xv = bs2f(x[(base + n) * 64 + lane]);
    mx = fmaxf(mx, xv * gates[n]);
  }
  red[w][lane] = mx;
  __syncthreads();
  if (tid < 64){
    float p = fmaxf(fmaxf(red[0][tid], red[1][tid]), fmaxf(red[2][tid], red[3][tid]));
    float o = twb[tid];
    red[0][tid] = p;
    __syncwarp();
    for (int d = 0; d < 64; d++) o += red[0][d] * twW[d * 64 + tid];
    xfm[b * 384 + off + tid] = fmaxf(o, 0.f);
  }
}

// ---------------- FM head ----------------
__global__ void k_fm(const float* __restrict__ xfm, const float* __restrict__ V,
                     const float* __restrict__ fw, const float* __restrict__ bu,
                     const float* __restrict__ bi, const float* __restrict__ b0,
                     const int* __restrict__ uid, const int* __restrict__ iid,
                     float* __restrict__ out){
  __shared__ float xsh[384];
  __shared__ float red[6];
  int b = blockIdx.x, j = threadIdx.x;
  xsh[j] = xfm[b * 384 + j];
  __syncthreads();
  float xv = 0.f, vv = 0.f;
  for (int k = 0; k < 384; k++){
    float xk = xsh[k];
    float v = V[k * 384 + j];
    xv += xk * v;
    vv += xk * xk * v * v;
  }
  float part = 0.5f * (xv * xv - vv) + xsh[j] * fw[j];
  part = wsum(part);
  int lane = j & 63, w = j >> 6;
  if (lane == 0) red[w] = part;
  __syncthreads();
  if (j == 0){
    float t = red[0] + red[1] + red[2] + red[3] + red[4] + red[5];
    t += bu[uid[b]] + bi[iid[b]] + b0[0];
    out[b] = t;
  }
}

extern "C" void kernel_launch(void* const* d_in, const int* in_sizes, int n_in,
                              void* d_out, int out_size, void* d_ws, size_t ws_size,
                              hipStream_t stream) {
  const int* uid      = (const int*)d_in[0];
  const int* iid      = (const int*)d_in[1];
  const int* u_nodes  = (const int*)d_in[2];
  const int* i_nodes  = (const int*)d_in[3];
  const int* u_ei     = (const int*)d_in[4];
  const int* i_ei     = (const int*)d_in[5];
  const int* u_et     = (const int*)d_in[6];
  const int* i_et     = (const int*)d_in[7];
  const float* user_emb = (const float*)d_in[10];
  const float* item_emb = (const float*)d_in[11];
  const float* word_emb = (const float*)d_in[12];
  const float* trans_u_W = (const float*)d_in[13];
  const float* trans_u_b = (const float*)d_in[14];
  const float* trans_i_W = (const float*)d_in[15];
  const float* trans_i_b = (const float*)d_in[16];
  const float* trans_w_W = (const float*)d_in[17];
  const float* trans_w_b = (const float*)d_in[18];
  const float* inter_u_W = (const float*)d_in[19];
  const float* inter_u_b = (const float*)d_in[20];
  const float* inter_i_W = (const float*)d_in[21];
  const float* inter_i_b = (const float*)d_in[22];
  const float* conv_u_W  = (const float*)d_in[23];
  const float* conv_u_b  = (const float*)d_in[24];
  const float* conv_u_att= (const float*)d_in[25];
  const float* conv_u_rel= (const float*)d_in[26];
  const float* conv_i_W  = (const float*)d_in[27];
  const float* conv_i_b  = (const float*)d_in[28];
  const float* conv_i_att= (const float*)d_in[29];
  const float* conv_i_rel= (const float*)d_in[30];
  const float* pool_W    = (const float*)d_in[31];
  const float* fm_w      = (const float*)d_in[32];
  const float* fm_V      = (const float*)d_in[33];
  const float* fm_bias_u = (const float*)d_in[34];
  const float* fm_bias_i = (const float*)d_in[35];
  const float* fm_bias   = (const float*)d_in[36];
  float* out = (float*)d_out;

  // workspace carve-up (16B-aligned chunks)
  char* w = (char*)d_ws;
  short* x0   = (short*)w;          w += (size_t)NN * 64 * 2;   // 16 MB
  short* x1   = (short*)w;          w += (size_t)NN * 64 * 2;   // 16 MB
  float* hbuf = (float*)w;          w += (size_t)NN * 64 * 4;   // 32 MB
  float* a0   = (float*)w;          w += (size_t)NN * 4;
  float* a1   = (float*)w;          w += (size_t)NN * 4;
  int* rowptr = (int*)w;            w += (size_t)(NN + 256) * 4;
  int* cursor = (int*)w;            w += (size_t)NN * 4;
  int* cnt    = (int*)w;            w += (size_t)NN * 4;
  int* csrc   = (int*)w;            w += (size_t)NE * 4;
  int* cet    = (int*)w;            w += (size_t)NE * 4;
  int* bsum   = (int*)w;            w += 4096;
  float* rtab = (float*)w;          w += 64;
  float* waA  = (float*)w;          w += 2 * 2 * 64 * 4;
  float* ba   = (float*)w;          w += 64;
  short8* cfrag = (short8*)w;       w += 2 * 4 * 2 * 64 * 16;   // conv frags (2 layers)
  short8* pfrag = (short8*)w;       w += 4 * 2 * 64 * 16;       // pool_W frags
  float* qbuf = (float*)w;          w += (size_t)2 * NB * 64 * 4;
  float* xfm  = (float*)w;          w += (size_t)NB * 384 * 4;

  k_wfrag<<<2, 256, 0, stream>>>(pool_W, pfrag, 1);

  for (int side = 0; side < 2; ++side){
    const int*  nodes = side ? i_nodes : u_nodes;
    const int*  ei    = side ? i_ei    : u_ei;
    const int*  et    = side ? i_et    : u_et;
    const float* convW = side ? conv_i_W   : conv_u_W;
    const float* convB = side ? conv_i_b   : conv_u_b;
    const float* att   = side ? conv_i_att : conv_u_att;
    const float* rel   = side ? conv_i_rel : conv_u_rel;
    const int*  ids   = side ? iid : uid;
    const float* emb  = side ? item_emb : user_emb;
    const float* intW = side ? inter_i_W : inter_u_W;
    const float* intB = side ? inter_i_b : inter_u_b;
    const float* trW  = side ? trans_i_W : trans_u_W;
    const float* trB  = side ? trans_i_b : trans_u_b;
    int repOff  = side ? 192 : 0;
    int poolOff = side ? 256 : 64;

    k_zero   <<<NN / 256, 256, 0, stream>>>(cnt, NN);
    k_hist   <<<NE / 256, 256, 0, stream>>>(ei, cnt);
    k_scan1  <<<NN / 256, 256, 0, stream>>>(cnt, rowptr, bsum);
    k_scan2  <<<1, 512, 0, stream>>>(bsum);
    k_scan3  <<<NN / 256, 256, 0, stream>>>(rowptr, bsum, cursor);
    k_scatter<<<NE / 256, 256, 0, stream>>>(ei, et, cursor, csrc, cet);
    k_gather <<<NN * 64 / 256, 256, 0, stream>>>(nodes, word_emb, x0);
    k_wfrag  <<<4, 256, 0, stream>>>(convW, cfrag, 2);
    k_wmisc  <<<1, 256, 0, stream>>>(convW, convB, att, rel, waA, ba, rtab);
    k_prep   <<<NB / 4, 256, 0, stream>>>(ids, emb, intW, intB, trW, trB, xfm, repOff, qbuf);

    short* A = x0; short* Bv = x1;
    for (int l = 0; l < 2; ++l){
      k_gemm_h<<<NN / 128, 256, 0, stream>>>(A, cfrag + l * 512, convB + l * 64,
                                             waA + l * 128, ba + l * 2, hbuf, a0, a1);
      k_agg   <<<NN / 4, 256, 0, stream>>>(rowptr, csrc, cet, a0, a1, rtab, l * 4,
                                           hbuf, Bv);
      k_scorepool<<<NB, 256, 0, stream>>>(Bv, pfrag, qbuf + (size_t)l * NB * 64,
                                          trans_w_W + l * 4096, trans_w_b + l * 64,
                                          xfm, poolOff + l * 64);
      short* t = A; A = Bv; Bv = t;
    }
  }

  k_fm<<<NB, 384, 0, stream>>>(xfm, fm_V, fm_w, fm_bias_u, fm_bias_i, fm_bias,
                               uid, iid, out);
}

// Round 4
// 539.023 us; speedup vs baseline: 3.0282x; 1.3946x over previous
//
#include <hip/hip_runtime.h>
#include <hip/hip_bf16.h>

#define NN 131072   // nodes per side
#define NE 524288   // edges per side
#define NB 1024     // batch (graphs per side)

typedef __attribute__((ext_vector_type(8))) short short8;   // 8 bf16
typedef __attribute__((ext_vector_type(4))) float f32x4;

__device__ __forceinline__ float wsum(float v){
#pragma unroll
  for (int o = 32; o > 0; o >>= 1) v += __shfl_xor(v, o, 64);
  return v;
}
__device__ __forceinline__ short f2bs(float f){
  __hip_bfloat16 t = __float2bfloat16(f);
  union { __hip_bfloat16 b; short s; } u; u.b = t; return u.s;
}
__device__ __forceinline__ float bs2f(short s){
  return __uint_as_float(((unsigned)(unsigned short)s) << 16);
}
__device__ __forceinline__ float ulo2f(unsigned v){ return __uint_as_float(v << 16); }
__device__ __forceinline__ float uhi2f(unsigned v){ return __uint_as_float(v & 0xFFFF0000u); }
__device__ __forceinline__ unsigned fpack(float x, float y){
  return (unsigned)(unsigned short)f2bs(x) | ((unsigned)(unsigned short)f2bs(y) << 16);
}

// ---------------- CSR build (both sides; global node = side*NN + n) ----------------
__global__ void k_zero(int* __restrict__ p){
  p[blockIdx.x * 256 + threadIdx.x] = 0;
}

__global__ void k_hist(const int* __restrict__ u_ei, const int* __restrict__ i_ei,
                       int* __restrict__ cnt){
  int ee = blockIdx.x * 256 + threadIdx.x;       // [0, 2NE)
  int side = ee >= NE;
  int e = ee - side * NE;
  const int* ei = side ? i_ei : u_ei;
  atomicAdd(&cnt[ei[NE + e] + side * NN], 1);
}

__global__ void k_scan1(const int* __restrict__ cnt, int* __restrict__ rowptr,
                        int* __restrict__ bsum){
  __shared__ int sh[256];
  int i = blockIdx.x * 256 + threadIdx.x;
  int v = cnt[i];
  sh[threadIdx.x] = v; __syncthreads();
  for (int off = 1; off < 256; off <<= 1){
    int t = (threadIdx.x >= off) ? sh[threadIdx.x - off] : 0;
    __syncthreads();
    sh[threadIdx.x] += t;
    __syncthreads();
  }
  int incl = sh[threadIdx.x];
  rowptr[i] = incl - v;
  if (threadIdx.x == 255) bsum[blockIdx.x] = incl;
}

__global__ void k_scan2(int* __restrict__ bsum){
  __shared__ int sh[1024];
  int v = bsum[threadIdx.x];
  sh[threadIdx.x] = v; __syncthreads();
  for (int off = 1; off < 1024; off <<= 1){
    int t = (threadIdx.x >= off) ? sh[threadIdx.x - off] : 0;
    __syncthreads();
    sh[threadIdx.x] += t;
    __syncthreads();
  }
  bsum[threadIdx.x] = sh[threadIdx.x] - v;  // exclusive
}

__global__ void k_scan3(int* __restrict__ rowptr, const int* __restrict__ bsum,
                        int* __restrict__ cursor){
  int i = blockIdx.x * 256 + threadIdx.x;
  int v = rowptr[i] + bsum[blockIdx.x];
  rowptr[i] = v;
  cursor[i] = v;
  if (i == 0) rowptr[2 * NN] = 2 * NE;
}

__global__ void k_scatter(const int* __restrict__ u_ei, const int* __restrict__ i_ei,
                          const int* __restrict__ u_et, const int* __restrict__ i_et,
                          int* __restrict__ cursor, int* __restrict__ pedge){
  int ee = blockIdx.x * 256 + threadIdx.x;
  int side = ee >= NE;
  int e = ee - side * NE;
  const int* ei = side ? i_ei : u_ei;
  const int* et = side ? i_et : u_et;
  int src = ei[e] + side * NN;
  int dst = ei[NE + e] + side * NN;
  int p = atomicAdd(&cursor[dst], 1);
  pedge[p] = src | (et[e] << 18);
}

// ---------------- feature gather: word_emb fp32 -> bf16 X (both sides) ----------------
__global__ void k_gather(const int* __restrict__ u_nodes, const int* __restrict__ i_nodes,
                         const float* __restrict__ wemb, unsigned* __restrict__ x32){
  int id = blockIdx.x * 256 + threadIdx.x;       // [0, 2NN*32)
  int n = id >> 5, c2 = id & 31;
  int side = n >= NN;
  int local = n - side * NN;
  int widx = (side ? i_nodes : u_nodes)[local];
  const float2* src = (const float2*)(wemb + (long)widx * 64);
  float2 v = src[c2];
  x32[id] = fpack(v.x, v.y);
}

// ---------------- weight prep: MFMA B-frags for 5 matrices + waA/ba/rtab both sides ----------------
__global__ void k_wprep(const float* __restrict__ cuW, const float* __restrict__ ciW,
                        const float* __restrict__ pW,
                        const float* __restrict__ cub, const float* __restrict__ cib,
                        const float* __restrict__ uatt, const float* __restrict__ iatt,
                        const float* __restrict__ urel, const float* __restrict__ irel,
                        short8* __restrict__ frag, float* __restrict__ waA,
                        float* __restrict__ ba, float* __restrict__ rtab){
  int blk = blockIdx.x, tid = threadIdx.x;
  if (blk < 10){
    // frag[mat*512 + ((t*2+hh)*64 + lane)][j] = bf16( W[k=hh*32+(lane>>4)*8+j][n=t*16+(lane&15)] )
    int mat = blk >> 1;
    const float* W = mat < 2 ? cuW + mat * 4096 : (mat < 4 ? ciW + (mat - 2) * 4096 : pW);
    int g = (blk & 1) * 256 + tid;     // [0,512)
    int lane = g & 63, rest = g >> 6;
    int hh = rest & 1, t = rest >> 1;
    int m = lane & 15, q = lane >> 4;
    short8 v;
#pragma unroll
    for (int j = 0; j < 8; j++)
      v[j] = f2bs(W[(hh * 32 + q * 8 + j) * 64 + (t * 16 + m)]);
    frag[mat * 512 + g] = v;
  } else {
    int side = blk - 10;
    const float* W    = side ? ciW : cuW;
    const float* bias = side ? cib : cub;
    const float* att  = side ? iatt : uatt;
    const float* rel  = side ? irel : urel;
    int l = tid >> 7, a = (tid >> 6) & 1, kk = tid & 63;
    float s = 0.f;
    for (int c = 0; c < 64; c++) s += W[l * 4096 + kk * 64 + c] * att[l * 192 + a * 64 + c];
    waA[((side * 2 + l) * 2 + a) * 64 + kk] = s;
    if (tid < 4){
      int l2 = tid >> 1, a2 = tid & 1;
      float sb = 0.f;
      for (int c = 0; c < 64; c++) sb += bias[l2 * 64 + c] * att[l2 * 192 + a2 * 64 + c];
      ba[(side * 2 + l2) * 2 + a2] = sb;
    }
    if (tid >= 4 && tid < 12){
      int id = tid - 4, l2 = id >> 2, tt = id & 3;
      float sr = 0.f;
      for (int c = 0; c < 64; c++) sr += rel[l2 * 256 + tt * 64 + c] * att[l2 * 192 + 128 + c];
      rtab[(side * 2 + l2) * 4 + tt] = sr;
    }
  }
}

// ---------------- per-interaction prep: rep (inter) + queries (both sides) ----------------
__global__ void k_prep(const int* __restrict__ uid, const int* __restrict__ iid,
                       const float* __restrict__ uemb, const float* __restrict__ iemb,
                       const float* __restrict__ uiW, const float* __restrict__ uib,
                       const float* __restrict__ iiW, const float* __restrict__ iib,
                       const float* __restrict__ utW, const float* __restrict__ utb,
                       const float* __restrict__ itW, const float* __restrict__ itb,
                       float* __restrict__ xfm, float* __restrict__ q){
  int lane = threadIdx.x & 63, w = threadIdx.x >> 6;
  int b = blockIdx.x * 4 + w;                     // [0, 2NB)
  int side = b >= NB;
  int lb = b - side * NB;
  const int* ids = side ? iid : uid;
  const float* emb = side ? iemb : uemb;
  const float* interW = side ? iiW : uiW;
  const float* interB = side ? iib : uib;
  const float* transW = side ? itW : utW;
  const float* transB = side ? itb : utb;
  int repOff = side ? 192 : 0;
  float xe = emb[(long)ids[lb] * 64 + lane];
  float o = interB[lane];
#pragma unroll
  for (int k = 0; k < 64; k++) o += __shfl(xe, k, 64) * interW[k * 64 + lane];
  xfm[lb * 384 + repOff + lane] = fmaxf(o, 0.f);
  for (int l = 0; l < 2; l++){
    float t = transB[l * 64 + lane];
#pragma unroll
    for (int k = 0; k < 64; k++) t += __shfl(xe, k, 64) * transW[l * 4096 + k * 64 + lane];
    q[((size_t)(side * 2 + l) * NB + lb) * 64 + lane] = fmaxf(t, 0.f);
  }
}

// ---------------- MFMA: h = x @ W + b (bf16 out) ; fused a0/a1 = x.waA + ba ----------------
__global__ __launch_bounds__(256) void k_gemm_h(
    const short* __restrict__ x, const short8* __restrict__ cfrag,
    const float* __restrict__ cub, const float* __restrict__ cib, int l,
    const float* __restrict__ waA_all, const float* __restrict__ ba_all,
    short* __restrict__ h, float* __restrict__ a0, float* __restrict__ a1){
  int bid = blockIdx.x;
  int side = bid >= (NN / 128);
  const short8* wfrag = cfrag + (side * 2 + l) * 512;
  const float* bias = (side ? cib : cub) + l * 64;
  const float* waA = waA_all + (side * 2 + l) * 128;
  const float* ba = ba_all + (side * 2 + l) * 2;
  int lane = threadIdx.x & 63, w = threadIdx.x >> 6;
  int m = lane & 15, q = lane >> 4;
  short8 Bf[4][2];
#pragma unroll
  for (int t = 0; t < 4; t++)
#pragma unroll
    for (int hh = 0; hh < 2; hh++)
      Bf[t][hh] = wfrag[(t * 2 + hh) * 64 + lane];
  float bs[4];
#pragma unroll
  for (int t = 0; t < 4; t++) bs[t] = bias[t * 16 + m];
  float w0[16], w1[16];
#pragma unroll
  for (int j = 0; j < 8; j++){
    w0[j]     = waA[q * 8 + j];
    w0[8 + j] = waA[32 + q * 8 + j];
    w1[j]     = waA[64 + q * 8 + j];
    w1[8 + j] = waA[96 + q * 8 + j];
  }
  float ba0 = ba[0], ba1 = ba[1];
  long n0 = (long)bid * 128 + w * 32;
  for (int rb = 0; rb < 2; rb++, n0 += 16){
    const short8* xr = (const short8*)(x + (n0 + m) * 64);
    short8 A0 = xr[q];
    short8 A1 = xr[q + 4];
    f32x4 acc[4];
#pragma unroll
    for (int t = 0; t < 4; t++){
      acc[t] = (f32x4){bs[t], bs[t], bs[t], bs[t]};
      acc[t] = __builtin_amdgcn_mfma_f32_16x16x32_bf16(A0, Bf[t][0], acc[t], 0, 0, 0);
      acc[t] = __builtin_amdgcn_mfma_f32_16x16x32_bf16(A1, Bf[t][1], acc[t], 0, 0, 0);
    }
#pragma unroll
    for (int t = 0; t < 4; t++)
#pragma unroll
      for (int r = 0; r < 4; r++)
        h[(n0 + q * 4 + r) * 64 + t * 16 + m] = f2bs(acc[t][r]);
    float p0 = 0.f, p1 = 0.f;
#pragma unroll
    for (int j = 0; j < 8; j++){
      float va = bs2f(A0[j]);
      float vb = bs2f(A1[j]);
      p0 += va * w0[j] + vb * w0[8 + j];
      p1 += va * w1[j] + vb * w1[8 + j];
    }
    p0 += __shfl_xor(p0, 16, 64); p0 += __shfl_xor(p0, 32, 64);
    p1 += __shfl_xor(p1, 16, 64); p1 += __shfl_xor(p1, 32, 64);
    if (q == 0){ a0[n0 + m] = p0 + ba0; a1[n0 + m] = p1 + ba1; }
  }
}

// ---------------- GAT aggregation: wave per dst node; paired 2-row gathers ----------------
__global__ __launch_bounds__(256) void k_agg(
    const int* __restrict__ rowptr, const int* __restrict__ pedge,
    const float* __restrict__ a0, const float* __restrict__ a1,
    const float* __restrict__ rtab, int l,
    const unsigned* __restrict__ h32, unsigned* __restrict__ xo32){
  int lane = threadIdx.x & 63, w = threadIdx.x >> 6;
  int n = blockIdx.x * 4 + w;                     // [0, 2NN)
  int side = n >= NN;
  const float* rt = rtab + (side * 2 + l) * 4;
  float rt0 = rt[0], rt1 = rt[1], rt2 = rt[2], rt3 = rt[3];
  int s0 = rowptr[n], s1 = rowptr[n + 1];
  int deg = s1 - s0;
  float a1n = a1[n];
  int c = lane & 31, half = lane >> 5;
  float accx = 0.f, accy = 0.f;
  int src = 0; float ex = 0.f; float den;
  bool fast = (deg <= 64);
  if (fast){
    if (lane < deg){
      int pe = pedge[s0 + lane];
      src = pe & 0x3FFFF;
      int et = (pe >> 18) & 3;
      float r = (et & 2) ? ((et & 1) ? rt3 : rt2) : ((et & 1) ? rt1 : rt0);
      float e = a0[src] + a1n + r;
      e = (e > 0.f) ? e : 0.2f * e;
      ex = __expf(e);
    }
    den = wsum(ex);
  } else {
    den = 0.f;
    for (int base = s0; base < s1; base += 64){
      int idx = base + lane;
      float exc = 0.f;
      if (idx < s1){
        int pe = pedge[idx];
        int sc = pe & 0x3FFFF;
        int et = (pe >> 18) & 3;
        float r = (et & 2) ? ((et & 1) ? rt3 : rt2) : ((et & 1) ? rt1 : rt0);
        float e = a0[sc] + a1n + r;
        e = (e > 0.f) ? e : 0.2f * e;
        exc = __expf(e);
      }
      den += wsum(exc);
    }
  }
  float inv = 1.f / (den + 1e-16f);
  if (fast){
    // lanes 0-31: edge j+half=even stream, 32-63: odd stream; 4 edges per iter
    for (int j = 0; j < deg; j += 4){
      int jA = j + half, jB = j + 2 + half;
      int sA = __shfl(src, jA, 64);
      float eA = __shfl(ex, jA, 64) * inv;
      int sB = __shfl(src, jB, 64);
      float eB = __shfl(ex, jB, 64) * inv;
      unsigned vA = h32[(long)sA * 32 + c];
      unsigned vB = h32[(long)sB * 32 + c];
      accx += eA * ulo2f(vA) + eB * ulo2f(vB);
      accy += eA * uhi2f(vA) + eB * uhi2f(vB);
    }
  } else {
    for (int base = s0; base < s1; base += 64){
      int idx = base + lane, cnt2 = min(64, s1 - base);
      int src2 = 0; float ex2 = 0.f;
      if (idx < s1){
        int pe = pedge[idx];
        src2 = pe & 0x3FFFF;
        int et = (pe >> 18) & 3;
        float r = (et & 2) ? ((et & 1) ? rt3 : rt2) : ((et & 1) ? rt1 : rt0);
        float e = a0[src2] + a1n + r;
        e = (e > 0.f) ? e : 0.2f * e;
        ex2 = __expf(e);
      }
      for (int j = 0; j < cnt2; j += 2){
        int jj = j + half;
        int s = __shfl(src2, jj, 64);
        float wgt = __shfl(ex2, jj, 64) * inv;
        unsigned v = h32[(long)s * 32 + c];
        accx += wgt * ulo2f(v);
        accy += wgt * uhi2f(v);
      }
    }
  }
  accx += __shfl_xor(accx, 32, 64);
  accy += __shfl_xor(accy, 32, 64);
  if (half == 0)
    xo32[(long)n * 32 + c] = fpack(fmaxf(accx, 0.f), fmaxf(accy, 0.f));
}

// ---------------- fused: y=x@poolW (MFMA), gate, gmp(x*gate), trans_w ----------------
__global__ __launch_bounds__(256) void k_scorepool(
    const short* __restrict__ x, const short8* __restrict__ frag,
    const float* __restrict__ qbuf, int l, const float* __restrict__ twW_all,
    const float* __restrict__ twb_all, float* __restrict__ xfm){
  __shared__ float gates[128];
  __shared__ float red[4][64];
  int b = blockIdx.x;                              // [0, 2NB)
  int side = b >= NB;
  int g = b - side * NB;
  const short8* pfrag = frag + 4 * 512;
  const float* q = qbuf + ((size_t)(side * 2 + l) * NB + g) * 64;
  const float* twW = twW_all + l * 4096;
  const float* twb = twb_all + l * 64;
  int off = (side ? 256 : 64) + l * 64;
  long base = (long)side * NN + (long)g * 128;
  int tid = threadIdx.x, lane = tid & 63, w = tid >> 6;
  int m = lane & 15, qd = lane >> 4;
  short8 Bf[4][2];
#pragma unroll
  for (int t = 0; t < 4; t++)
#pragma unroll
    for (int hh = 0; hh < 2; hh++)
      Bf[t][hh] = pfrag[(t * 2 + hh) * 64 + lane];
  float qv[4];
#pragma unroll
  for (int t = 0; t < 4; t++) qv[t] = q[t * 16 + m];
  for (int rb = 0; rb < 2; rb++){
    long n0 = base + w * 32 + rb * 16;
    const short8* xr = (const short8*)(x + (n0 + m) * 64);
    short8 A0 = xr[qd];
    short8 A1 = xr[qd + 4];
    f32x4 acc[4];
#pragma unroll
    for (int t = 0; t < 4; t++){
      acc[t] = (f32x4){0.f, 0.f, 0.f, 0.f};
      acc[t] = __builtin_amdgcn_mfma_f32_16x16x32_bf16(A0, Bf[t][0], acc[t], 0, 0, 0);
      acc[t] = __builtin_amdgcn_mfma_f32_16x16x32_bf16(A1, Bf[t][1], acc[t], 0, 0, 0);
    }
#pragma unroll
    for (int r = 0; r < 4; r++){
      float p = acc[0][r] * qv[0] + acc[1][r] * qv[1] + acc[2][r] * qv[2] + acc[3][r] * qv[3];
      p += __shfl_xor(p, 1, 64); p += __shfl_xor(p, 2, 64);
      p += __shfl_xor(p, 4, 64); p += __shfl_xor(p, 8, 64);
      if (m == 0)
        gates[w * 32 + rb * 16 + qd * 4 + r] = 1.f / (1.f + __expf(-p * 0.125f));
    }
  }
  __syncthreads();
  const unsigned* x32 = (const unsigned*)x;
  int c = lane & 31, half = lane >> 5;
  float mxx = 0.f, mxy = 0.f;
  for (int p = 0; p < 16; p++){
    int nn = w * 32 + 2 * p + half;
    unsigned v = x32[(base + nn) * 32 + c];
    float gt = gates[nn];
    mxx = fmaxf(mxx, ulo2f(v) * gt);
    mxy = fmaxf(mxy, uhi2f(v) * gt);
  }
  mxx = fmaxf(mxx, __shfl_xor(mxx, 32, 64));
  mxy = fmaxf(mxy, __shfl_xor(mxy, 32, 64));
  if (half == 0){ red[w][2 * c] = mxx; red[w][2 * c + 1] = mxy; }
  __syncthreads();
  if (tid < 64){
    float p = fmaxf(fmaxf(red[0][tid], red[1][tid]), fmaxf(red[2][tid], red[3][tid]));
    float o = twb[tid];
    red[0][tid] = p;
    __syncwarp();
    for (int d = 0; d < 64; d++) o += red[0][d] * twW[d * 64 + tid];
    xfm[g * 384 + off + tid] = fmaxf(o, 0.f);
  }
}

// ---------------- FM head ----------------
__global__ void k_fm(const float* __restrict__ xfm, const float* __restrict__ V,
                     const float* __restrict__ fw, const float* __restrict__ bu,
                     const float* __restrict__ bi, const float* __restrict__ b0,
                     const int* __restrict__ uid, const int* __restrict__ iid,
                     float* __restrict__ out){
  __shared__ float xsh[384];
  __shared__ float red[6];
  int b = blockIdx.x, j = threadIdx.x;
  xsh[j] = xfm[b * 384 + j];
  __syncthreads();
  float xv = 0.f, vv = 0.f;
  for (int k = 0; k < 384; k++){
    float xk = xsh[k];
    float v = V[k * 384 + j];
    float pk = xk * v;
    xv += pk;
    vv += pk * pk;
  }
  float part = 0.5f * (xv * xv - vv) + xsh[j] * fw[j];
  part = wsum(part);
  int lane = j & 63, w = j >> 6;
  if (lane == 0) red[w] = part;
  __syncthreads();
  if (j == 0){
    float t = red[0] + red[1] + red[2] + red[3] + red[4] + red[5];
    t += bu[uid[b]] + bi[iid[b]] + b0[0];
    out[b] = t;
  }
}

extern "C" void kernel_launch(void* const* d_in, const int* in_sizes, int n_in,
                              void* d_out, int out_size, void* d_ws, size_t ws_size,
                              hipStream_t stream) {
  const int* uid      = (const int*)d_in[0];
  const int* iid      = (const int*)d_in[1];
  const int* u_nodes  = (const int*)d_in[2];
  const int* i_nodes  = (const int*)d_in[3];
  const int* u_ei     = (const int*)d_in[4];
  const int* i_ei     = (const int*)d_in[5];
  const int* u_et     = (const int*)d_in[6];
  const int* i_et     = (const int*)d_in[7];
  const float* user_emb = (const float*)d_in[10];
  const float* item_emb = (const float*)d_in[11];
  const float* word_emb = (const float*)d_in[12];
  const float* trans_u_W = (const float*)d_in[13];
  const float* trans_u_b = (const float*)d_in[14];
  const float* trans_i_W = (const float*)d_in[15];
  const float* trans_i_b = (const float*)d_in[16];
  const float* trans_w_W = (const float*)d_in[17];
  const float* trans_w_b = (const float*)d_in[18];
  const float* inter_u_W = (const float*)d_in[19];
  const float* inter_u_b = (const float*)d_in[20];
  const float* inter_i_W = (const float*)d_in[21];
  const float* inter_i_b = (const float*)d_in[22];
  const float* conv_u_W  = (const float*)d_in[23];
  const float* conv_u_b  = (const float*)d_in[24];
  const float* conv_u_att= (const float*)d_in[25];
  const float* conv_u_rel= (const float*)d_in[26];
  const float* conv_i_W  = (const float*)d_in[27];
  const float* conv_i_b  = (const float*)d_in[28];
  const float* conv_i_att= (const float*)d_in[29];
  const float* conv_i_rel= (const float*)d_in[30];
  const float* pool_W    = (const float*)d_in[31];
  const float* fm_w      = (const float*)d_in[32];
  const float* fm_V      = (const float*)d_in[33];
  const float* fm_bias_u = (const float*)d_in[34];
  const float* fm_bias_i = (const float*)d_in[35];
  const float* fm_bias   = (const float*)d_in[36];
  float* out = (float*)d_out;

  // workspace carve-up (all chunks multiples of 16 B)
  char* w = (char*)d_ws;
  short* X0   = (short*)w;          w += (size_t)2 * NN * 64 * 2;   // 32 MB
  short* X1   = (short*)w;          w += (size_t)2 * NN * 64 * 2;   // 32 MB
  short* H    = (short*)w;          w += (size_t)2 * NN * 64 * 2;   // 32 MB
  int* pedge  = (int*)w;            w += (size_t)2 * NE * 4;        // 4 MB
  float* a0   = (float*)w;          w += (size_t)2 * NN * 4;
  float* a1   = (float*)w;          w += (size_t)2 * NN * 4;
  int* rowptr = (int*)w;            w += (size_t)(2 * NN + 256) * 4;
  int* cursor = (int*)w;            w += (size_t)2 * NN * 4;
  int* cnt    = (int*)w;            w += (size_t)2 * NN * 4;
  int* bsum   = (int*)w;            w += 1024 * 4;
  short8* frag = (short8*)w;        w += (size_t)5 * 512 * 16;      // 5 matrices
  float* waA  = (float*)w;          w += 2 * 2 * 2 * 64 * 4;
  float* ba   = (float*)w;          w += 64;
  float* rtab = (float*)w;          w += 64;
  float* qbuf = (float*)w;          w += (size_t)4 * NB * 64 * 4;
  float* xfm  = (float*)w;          w += (size_t)NB * 384 * 4;

  k_wprep  <<<12, 256, 0, stream>>>(conv_u_W, conv_i_W, pool_W, conv_u_b, conv_i_b,
                                    conv_u_att, conv_i_att, conv_u_rel, conv_i_rel,
                                    frag, waA, ba, rtab);
  k_zero   <<<2 * NN / 256, 256, 0, stream>>>(cnt);
  k_hist   <<<2 * NE / 256, 256, 0, stream>>>(u_ei, i_ei, cnt);
  k_scan1  <<<2 * NN / 256, 256, 0, stream>>>(cnt, rowptr, bsum);
  k_scan2  <<<1, 1024, 0, stream>>>(bsum);
  k_scan3  <<<2 * NN / 256, 256, 0, stream>>>(rowptr, bsum, cursor);
  k_scatter<<<2 * NE / 256, 256, 0, stream>>>(u_ei, i_ei, u_et, i_et, cursor, pedge);
  k_gather <<<2 * NN * 32 / 256, 256, 0, stream>>>(u_nodes, i_nodes, word_emb,
                                                   (unsigned*)X0);
  k_prep   <<<2 * NB / 4, 256, 0, stream>>>(uid, iid, user_emb, item_emb,
                                            inter_u_W, inter_u_b, inter_i_W, inter_i_b,
                                            trans_u_W, trans_u_b, trans_i_W, trans_i_b,
                                            xfm, qbuf);

  short* A = X0; short* Bv = X1;
  for (int l = 0; l < 2; ++l){
    k_gemm_h<<<2 * NN / 128, 256, 0, stream>>>(A, frag, conv_u_b, conv_i_b, l,
                                               waA, ba, H, a0, a1);
    k_agg   <<<2 * NN / 4, 256, 0, stream>>>(rowptr, pedge, a0, a1, rtab, l,
                                             (const unsigned*)H, (unsigned*)Bv);
    k_scorepool<<<2 * NB, 256, 0, stream>>>(Bv, frag, qbuf, l, trans_w_W, trans_w_b, xfm);
    short* t = A; A = Bv; Bv = t;
  }

  k_fm<<<NB, 384, 0, stream>>>(xfm, fm_V, fm_w, fm_bias_u, fm_bias_i, fm_bias,
                               uid, iid, out);
}